// Round 8
// baseline (1680.179 us; speedup 1.0000x reference)
//
#include <hip/hip_runtime.h>

#define T_STEPS 1024
#define B_SEQ   4096

typedef float v2f __attribute__((ext_vector_type(2)));

// ds_swizzle BitMode (fallback only): lane' = lane ^ m -> offset (m<<10)|0x1F
#define SWZ(x, IMM) __int_as_float(__builtin_amdgcn_ds_swizzle(__float_as_int(x), IMM))

__device__ __forceinline__ v2f pkfma(v2f a, v2f b, v2f c) {
    return __builtin_elementwise_fma(a, b, c);
}

// Runtime dtype sniff (insurance; evidence says inputs are f32).
__device__ __forceinline__ bool sniff_is_bf16(const void* p) {
    unsigned short h = ((const unsigned short*)p)[threadIdx.x & 63];
    union { unsigned u; float f; } c; c.u = ((unsigned)h) << 16;
    float f = fabsf(c.f);
    bool bad = !(f <= 1e4f) || (f != 0.0f && f < 1e-10f);
    return __ballot(bad) == 0ULL;
}

__device__ __forceinline__ float ldf(const void* p, long long i, bool isbf) {
    if (isbf) {
        unsigned short h = ((const unsigned short*)p)[i];
        union { unsigned u; float f; } c; c.u = ((unsigned)h) << 16;
        return c.f;
    }
    return ((const float*)p)[i];
}

__device__ __forceinline__ float bfc(unsigned short h) {
    union { unsigned u; float f; } c; c.u = ((unsigned)h) << 16;
    return c.f;
}

// 64-thread single-wave blocks; ONE sequence per block (lanes 32-63 mirror
// lanes 0-31) -> 4096 waves = 4 waves/SIMD for latency hiding.
// lane role: j = tid&15, net = (tid>>4)&1
__global__ __launch_bounds__(64, 4) void reac_rk4_kernel(
    const void* __restrict__ u_,     const void* __restrict__ xz0_,
    const void* __restrict__ r1_W0_, const void* __restrict__ r1_b0_,
    const void* __restrict__ r1_W1_, const void* __restrict__ r1_b1_,
    const void* __restrict__ r1_W2_, const void* __restrict__ r1_b2_,
    const void* __restrict__ r2_W0_, const void* __restrict__ r2_b0_,
    const void* __restrict__ r2_W1_, const void* __restrict__ r2_b1_,
    const void* __restrict__ r2_W2_, const void* __restrict__ r2_b2_,
    const void* __restrict__ ymean_, const void* __restrict__ ystd_,
    const void* __restrict__ umean_, const void* __restrict__ ustd_,
    float* __restrict__ out)
{
    const int tid = threadIdx.x;
    const int j   = tid & 15;
    const int net = (tid >> 4) & 1;
    const long long b = blockIdx.x;

    const bool vW = sniff_is_bf16(r1_W1_);
    const bool vU = sniff_is_bf16(u_);
    const bool vX = sniff_is_bf16(xz0_);

    // 2*log2(e): folded into layer-1/2 weights so tanh needs no leading mul.
    const float KK = 2.88539008177793f;

    // ---- per-lane weights ----
    float w0a, w0b, b0;
    if (net) { w0a = ldf(r2_W0_, j, vW); w0b = ldf(r2_W0_, 16 + j, vW); b0 = ldf(r2_b0_, j, vW); }
    else     { w0a = ldf(r1_W0_, j, vW); w0b = 0.0f;                    b0 = ldf(r1_b0_, j, vW); }
    w0a *= KK; w0b *= KK; b0 *= KK;   // exp2 arg pre-scaled

    const void* W1 = net ? r2_W1_ : r1_W1_;
    // Rotation-ordered weights: w16[r] = W1[(j-r)&15][j]  (16 VGPRs)
    float w16[16];
    #pragma unroll
    for (int r = 0; r < 16; ++r)
        w16[r] = ldf(W1, ((j - r) & 15) * 16 + j, vW);
    // h = 1 - 2r fold: acc = KK*(b1 + sum_i W) - 2*KK*sum_i W*r_i
    float wsum = 0.0f;
    #pragma unroll
    for (int r = 0; r < 16; ++r) wsum += w16[r];
    const float b1v = KK * (ldf(net ? r2_b1_ : r1_b1_, j, vW) + wsum);
    {
        const float m2k = -2.0f * KK;
        #pragma unroll
        for (int r = 0; r < 16; ++r) w16[r] *= m2k;
    }

    const float Camean = ldf(ymean_, 0, vW), Cbmean = ldf(ymean_, 1, vW);
    const float Castd  = ldf(ystd_,  0, vW), Cbstd  = ldf(ystd_,  1, vW);
    const float um     = ldf(umean_, 0, vW), us     = ldf(ustd_,  0, vW);
    const float invCastd = 1.0f / Castd, invCbstd = 1.0f / Cbstd;

    // layer-3: RAW net output (normalized-space physics); tanh completion folded:
    // p_lane = w2*(1-2r) + b2/16 = fma(-2*w2, r, w2 + b2/16)
    const float w2  = ldf(net ? r2_W2_ : r1_W2_, j, vW);
    const float b2  = ldf(net ? r2_b2_ : r1_b2_, 0, vW);
    const float w2m = -2.0f * w2;
    const float w2p = w2 + 0.0625f * b2;

    // normalized-space physics constants:
    // kA = fma(-F,Ca,cA(t)) - f1 ; kB = fma(-F,Cb,cB) + fma(-3,f2,fma(f1,sAB,.)) ; kC = fma(-F,Cc,cB) + f2
    const float alpha = 0.1f * us * invCastd;
    const float beta  = 0.1f * (um - Camean) * invCastd;
    const float cB    = -0.1f * Cbmean * invCbstd;
    const float sAB   = Castd * invCbstd;

    // ---- state: (Ca,Cb) packed + Cc scalar, replicated over all 64 lanes ----
    v2f   Cab = { ldf(xz0_, b * 3 + 0, vX), ldf(xz0_, b * 3 + 1, vX) };
    float Cc  =   ldf(xz0_, b * 3 + 2, vX);

    // ---- output lanes (0..4 only): c=0,1 -> yseq; c=2,3,4 -> xseq ----
    const int  c      = tid & 31;
    const bool active = (tid < 5);
    float* sp;
    int sstr;
    if (c < 2) { sp = out + b * (T_STEPS * 2) + c;                                        sstr = 2; }
    else       { sp = out + (long long)B_SEQ * T_STEPS * 2 + b * (T_STEPS * 3) + (c - 2); sstr = 3; }
    const bool selA = (c == 0) | (c == 2);
    const bool selB = (c == 1) | (c == 3);

    const long long ubase = b * T_STEPS;

    const v2f HALF2  = { 0.5f, 0.5f };
    const v2f TWO2   = { 2.0f, 2.0f };
    const v2f SIXTH2 = { 1.0f / 6.0f, 1.0f / 6.0f };

    // One RK4 stage. DPP fused into VOP2 mul/fmac/add, with explicit wait
    // states for the VALU-write -> DPP-read hazard (compiler can't see into asm).
    auto fxu = [&](v2f xab, float xc, float cvx, v2f& kab, float& kc) {
        float A0 = net ? xab.y : xab.x;
        // input-only physics terms (ready before f1/f2; schedules into gaps)
        float kvx = fmaf(-0.1f, xab.x, cvx);
        float kvy = fmaf(-0.1f, xab.y, cB);
        float kvc = fmaf(-0.1f, xc,    cB);
        // layer 1: r = rcp(exp2(pre-scaled arg)+1); h = 1-2r folded into W1/b1
        float e1  = __builtin_amdgcn_exp2f(fmaf(w0a, A0, fmaf(w0b, xc, b0)));
        float rr1 = __builtin_amdgcn_rcpf(e1 + 1.0f);

        // 16x16 matvec: 4 independent DPP-fused fmac chains (depth 4).
        // s_nop 1 at top = 2 wait states after v_rcp writes rr1 (DPP src hazard).
        float acc0 = fmaf(rr1, w16[0], b1v);
        float acc1, acc2, acc3;
        asm("s_nop 1\n\t"
            "v_mul_f32_dpp %1, %4, %5 row_ror:1 row_mask:0xf bank_mask:0xf\n\t"
            "v_mul_f32_dpp %2, %4, %6 row_ror:2 row_mask:0xf bank_mask:0xf\n\t"
            "v_mul_f32_dpp %3, %4, %7 row_ror:3 row_mask:0xf bank_mask:0xf\n\t"
            "v_fmac_f32_dpp %0, %4, %8 row_ror:4 row_mask:0xf bank_mask:0xf\n\t"
            "v_fmac_f32_dpp %1, %4, %9 row_ror:5 row_mask:0xf bank_mask:0xf\n\t"
            "v_fmac_f32_dpp %2, %4, %10 row_ror:6 row_mask:0xf bank_mask:0xf\n\t"
            "v_fmac_f32_dpp %3, %4, %11 row_ror:7 row_mask:0xf bank_mask:0xf\n\t"
            "v_fmac_f32_dpp %0, %4, %12 row_ror:8 row_mask:0xf bank_mask:0xf\n\t"
            "v_fmac_f32_dpp %1, %4, %13 row_ror:9 row_mask:0xf bank_mask:0xf\n\t"
            "v_fmac_f32_dpp %2, %4, %14 row_ror:10 row_mask:0xf bank_mask:0xf\n\t"
            "v_fmac_f32_dpp %3, %4, %15 row_ror:11 row_mask:0xf bank_mask:0xf\n\t"
            "v_fmac_f32_dpp %0, %4, %16 row_ror:12 row_mask:0xf bank_mask:0xf\n\t"
            "v_fmac_f32_dpp %1, %4, %17 row_ror:13 row_mask:0xf bank_mask:0xf\n\t"
            "v_fmac_f32_dpp %2, %4, %18 row_ror:14 row_mask:0xf bank_mask:0xf\n\t"
            "v_fmac_f32_dpp %3, %4, %19 row_ror:15 row_mask:0xf bank_mask:0xf"
            : "+v"(acc0), "=&v"(acc1), "=&v"(acc2), "=&v"(acc3)
            : "v"(rr1),
              "v"(w16[1]),  "v"(w16[2]),  "v"(w16[3]),  "v"(w16[4]),  "v"(w16[5]),
              "v"(w16[6]),  "v"(w16[7]),  "v"(w16[8]),  "v"(w16[9]),  "v"(w16[10]),
              "v"(w16[11]), "v"(w16[12]), "v"(w16[13]), "v"(w16[14]), "v"(w16[15]));
        float s = (acc0 + acc1) + (acc2 + acc3);

        // layer 2 tanh + layer 3 lane term, folded: p = fma(-2w2, r, w2 + b2/16)
        float e2  = __builtin_amdgcn_exp2f(s);
        float r2r = __builtin_amdgcn_rcpf(e2 + 1.0f);
        float p   = fmaf(w2m, r2r, w2p);
        // circular rotate-reduce over the 16-lane net group (ping-pong + waits)
        float q;
        asm("s_nop 1\n\t"
            "v_add_f32_dpp %1, %0, %0 row_ror:8 row_mask:0xf bank_mask:0xf\n\t"
            "s_nop 1\n\t"
            "v_add_f32_dpp %0, %1, %1 row_ror:4 row_mask:0xf bank_mask:0xf\n\t"
            "s_nop 1\n\t"
            "v_add_f32_dpp %1, %0, %0 row_ror:2 row_mask:0xf bank_mask:0xf\n\t"
            "s_nop 1\n\t"
            "v_add_f32_dpp %0, %1, %1 row_ror:1 row_mask:0xf bank_mask:0xf\n\t"
            "s_nop 1"
            : "+v"(p), "=&v"(q));
        float ov = p;
        // net exchange: r1 <-> r2 across the 16-lane row pair
#if __has_builtin(__builtin_amdgcn_permlane16_swap)
        auto pr = __builtin_amdgcn_permlane16_swap(__float_as_uint(ov), __float_as_uint(ov), false, false);
        float other = __uint_as_float(net ? pr[0] : pr[1]);
#else
        float other = SWZ(ov, 0x401F);
#endif
        float f1 = net ? other : ov;   // raw fnn1
        float f2 = net ? ov : other;   // raw fnn2

        // normalized-space physics (scalar fma chains)
        kab.x = kvx - f1;
        kab.y = fmaf(-3.0f, f2, fmaf(f1, sAB, kvy));
        kc    = kvc + f2;
    };

    // one full RK4 step (store first, then advance)
    auto step = [&](float ut) {
        float cvx = fmaf(alpha, ut, beta);
        v2f k1ab, k2ab, k3ab, k4ab;
        float k1c, k2c, k3c, k4c;
        fxu(Cab, Cc, cvx, k1ab, k1c);
        fxu(pkfma(HALF2, k1ab, Cab), fmaf(0.5f, k1c, Cc), cvx, k2ab, k2c);
        fxu(pkfma(HALF2, k2ab, Cab), fmaf(0.5f, k2c, Cc), cvx, k3ab, k3c);
        fxu(Cab + k3ab, Cc + k3c, cvx, k4ab, k4c);
        v2f   sab = pkfma(TWO2, k2ab + k3ab, k1ab) + k4ab;
        float sc  = fmaf(2.0f, k2c + k3c, k1c) + k4c;
        Cab = pkfma(SIXTH2, sab, Cab);
        Cc  = fmaf(1.0f / 6.0f, sc, Cc);
    };
    auto emit = [&]() {
        float v = selA ? Cab.x : (selB ? Cab.y : Cc);
        if (active) { *sp = v; sp += sstr; }
    };
    // load u[t4 .. t4+3] (vectorized; ubase+t4 is 16B-aligned since t4%4==0)
    float uq[4];
    auto load_u4 = [&](int t4) {
        if (vU) {
            const unsigned short* pu = (const unsigned short*)u_ + (ubase + t4);
            ushort4 raw = *reinterpret_cast<const ushort4*>(pu);
            uq[0] = bfc(raw.x); uq[1] = bfc(raw.y); uq[2] = bfc(raw.z); uq[3] = bfc(raw.w);
        } else {
            const float* pf = (const float*)u_ + (ubase + t4);
            float4 raw = *reinterpret_cast<const float4*>(pf);
            uq[0] = raw.x; uq[1] = raw.y; uq[2] = raw.z; uq[3] = raw.w;
        }
    };

    // main loop: full 4-step blocks, no per-step termination check
    for (int t4 = 0; t4 < T_STEPS - 4; t4 += 4) {
        load_u4(t4);
        #pragma unroll
        for (int tb = 0; tb < 4; ++tb) {
            emit();
            step(uq[tb]);
        }
    }
    // tail block: steps 1020..1022 advance, 1023 store-only
    load_u4(T_STEPS - 4);
    #pragma unroll
    for (int tb = 0; tb < 3; ++tb) {
        emit();
        step(uq[tb]);
    }
    emit();
}

extern "C" void kernel_launch(void* const* d_in, const int* in_sizes, int n_in,
                              void* d_out, int out_size, void* d_ws, size_t ws_size,
                              hipStream_t stream) {
    (void)in_sizes; (void)n_in; (void)out_size; (void)d_ws; (void)ws_size;
    dim3 grid(B_SEQ);
    dim3 block(64);
    reac_rk4_kernel<<<grid, block, 0, stream>>>(
        d_in[0],  d_in[1],
        d_in[2],  d_in[3],  d_in[4],  d_in[5],  d_in[6],  d_in[7],
        d_in[8],  d_in[9],  d_in[10], d_in[11], d_in[12], d_in[13],
        d_in[14], d_in[15], d_in[16], d_in[17],
        (float*)d_out);
}

// Round 9
// 990.461 us; speedup vs baseline: 1.6964x; 1.6964x over previous
//
#include <hip/hip_runtime.h>

#define T_STEPS 1024
#define B_SEQ   4096

typedef float v2f __attribute__((ext_vector_type(2)));

// ds_swizzle BitMode (fallback only): lane' = lane ^ m -> offset (m<<10)|0x1F
#define SWZ(x, IMM) __int_as_float(__builtin_amdgcn_ds_swizzle(__float_as_int(x), IMM))

__device__ __forceinline__ v2f pkfma(v2f a, v2f b, v2f c) {
    return __builtin_elementwise_fma(a, b, c);
}

// Runtime dtype sniff (insurance; evidence says inputs are f32).
__device__ __forceinline__ bool sniff_is_bf16(const void* p) {
    unsigned short h = ((const unsigned short*)p)[threadIdx.x & 63];
    union { unsigned u; float f; } c; c.u = ((unsigned)h) << 16;
    float f = fabsf(c.f);
    bool bad = !(f <= 1e4f) || (f != 0.0f && f < 1e-10f);
    return __ballot(bad) == 0ULL;
}

__device__ __forceinline__ float ldf(const void* p, long long i, bool isbf) {
    if (isbf) {
        unsigned short h = ((const unsigned short*)p)[i];
        union { unsigned u; float f; } c; c.u = ((unsigned)h) << 16;
        return c.f;
    }
    return ((const float*)p)[i];
}

__device__ __forceinline__ float bfc(unsigned short h) {
    union { unsigned u; float f; } c; c.u = ((unsigned)h) << 16;
    return c.f;
}

// 64-thread single-wave blocks; 2 sequences per block (issue-bound: maximize
// sequences per wave — R8 proved 1 seq/wave doubles total issue and time).
// lane = seq_local*32 + net*16 + j
__global__ __launch_bounds__(64, 2) void reac_rk4_kernel(
    const void* __restrict__ u_,     const void* __restrict__ xz0_,
    const void* __restrict__ r1_W0_, const void* __restrict__ r1_b0_,
    const void* __restrict__ r1_W1_, const void* __restrict__ r1_b1_,
    const void* __restrict__ r1_W2_, const void* __restrict__ r1_b2_,
    const void* __restrict__ r2_W0_, const void* __restrict__ r2_b0_,
    const void* __restrict__ r2_W1_, const void* __restrict__ r2_b1_,
    const void* __restrict__ r2_W2_, const void* __restrict__ r2_b2_,
    const void* __restrict__ ymean_, const void* __restrict__ ystd_,
    const void* __restrict__ umean_, const void* __restrict__ ustd_,
    float* __restrict__ out)
{
    const int tid = threadIdx.x;
    const int j   = tid & 15;
    const int net = (tid >> 4) & 1;
    const long long b = (long long)blockIdx.x * 2 + (tid >> 5);

    const bool vW = sniff_is_bf16(r1_W1_);
    const bool vU = sniff_is_bf16(u_);
    const bool vX = sniff_is_bf16(xz0_);

    // 2*log2(e): folded into layer-1/2 weights so tanh needs no leading mul.
    const float KK = 2.88539008177793f;

    // ---- per-lane weights ----
    float w0a, w0b, b0;
    if (net) { w0a = ldf(r2_W0_, j, vW); w0b = ldf(r2_W0_, 16 + j, vW); b0 = ldf(r2_b0_, j, vW); }
    else     { w0a = ldf(r1_W0_, j, vW); w0b = 0.0f;                    b0 = ldf(r1_b0_, j, vW); }
    w0a *= KK; w0b *= KK; b0 *= KK;   // exp2 arg pre-scaled

    const void* W1 = net ? r2_W1_ : r1_W1_;
    // Rotation-ordered weights: w16[r] = W1[(j-r)&15][j]  (16 VGPRs)
    float w16[16];
    #pragma unroll
    for (int r = 0; r < 16; ++r)
        w16[r] = ldf(W1, ((j - r) & 15) * 16 + j, vW);
    // h = 1 - 2r fold: acc = KK*(b1 + sum_i W) - 2*KK*sum_i W*r_i
    float wsum = 0.0f;
    #pragma unroll
    for (int r = 0; r < 16; ++r) wsum += w16[r];
    const float b1v = KK * (ldf(net ? r2_b1_ : r1_b1_, j, vW) + wsum);
    {
        const float m2k = -2.0f * KK;
        #pragma unroll
        for (int r = 0; r < 16; ++r) w16[r] *= m2k;
    }

    const float Camean = ldf(ymean_, 0, vW), Cbmean = ldf(ymean_, 1, vW);
    const float Castd  = ldf(ystd_,  0, vW), Cbstd  = ldf(ystd_,  1, vW);
    const float um     = ldf(umean_, 0, vW), us     = ldf(ustd_,  0, vW);
    const float invCastd = 1.0f / Castd, invCbstd = 1.0f / Cbstd;

    // layer-3: RAW net output (normalized-space physics); tanh completion folded:
    // p_lane = w2*(1-2r) + b2/16 = fma(-2*w2, r, w2 + b2/16)
    const float w2  = ldf(net ? r2_W2_ : r1_W2_, j, vW);
    const float b2  = ldf(net ? r2_b2_ : r1_b2_, 0, vW);
    const float w2m = -2.0f * w2;
    const float w2p = w2 + 0.0625f * b2;

    // normalized-space physics constants:
    // kA = fma(-F,Ca,cA(t)) - f1 ; kB = fma(-F,Cb,cB) + fma(-3,f2,fma(f1,sAB,.)) ; kC = fma(-F,Cc,cB) + f2
    const float alpha = 0.1f * us * invCastd;
    const float beta  = 0.1f * (um - Camean) * invCastd;
    const float cB    = -0.1f * Cbmean * invCbstd;
    const float sAB   = Castd * invCbstd;
    const float mF    = -0.1f;   // VGPR-resident for asm use (VOP3 forbids literals)

    // ---- state: (Ca,Cb) packed + Cc scalar, replicated over the 32 lanes ----
    v2f   Cab = { ldf(xz0_, b * 3 + 0, vX), ldf(xz0_, b * 3 + 1, vX) };
    float Cc  =   ldf(xz0_, b * 3 + 2, vX);

    // ---- output lanes: c=0,1 -> yseq; c=2,3,4 -> xseq ----
    const int  c      = tid & 31;
    const bool active = (c < 5);
    float* sp;
    int sstr;
    if (c < 2) { sp = out + b * (T_STEPS * 2) + c;                                        sstr = 2; }
    else       { sp = out + (long long)B_SEQ * T_STEPS * 2 + b * (T_STEPS * 3) + (c - 2); sstr = 3; }
    const bool selA = (c == 0) | (c == 2);
    const bool selB = (c == 1) | (c == 3);

    const long long ubase = b * T_STEPS;

    const v2f HALF2  = { 0.5f, 0.5f };
    const v2f TWO2   = { 2.0f, 2.0f };
    const v2f SIXTH2 = { 1.0f / 6.0f, 1.0f / 6.0f };

    // One RK4 stage. DPP fused into VOP2 mul/fmac/add. The rcp->DPP hazard
    // window is covered by the 3 independent physics fmas (kvx/kvy/kvc) issued
    // INSIDE the asm block (useful work instead of s_nop).
    auto fxu = [&](v2f xab, float xc, float cvx, v2f& kab, float& kc) {
        float A0 = net ? xab.y : xab.x;
        // layer 1: r = rcp(exp2(pre-scaled arg)+1); h = 1-2r folded into W1/b1
        float e1  = __builtin_amdgcn_exp2f(fmaf(w0a, A0, fmaf(w0b, xc, b0)));
        float rr1 = __builtin_amdgcn_rcpf(e1 + 1.0f);

        // 16x16 matvec: 4 independent DPP-fused fmac chains (depth 4).
        // First 3 instrs (kv* fmas, independent of rr1) provide the >=2 wait
        // states after v_rcp writes rr1 before the first DPP read of rr1.
        float acc0 = fmaf(rr1, w16[0], b1v);
        float acc1, acc2, acc3, kvx, kvy, kvc;
        asm("v_fma_f32 %4, %23, %24, %27\n\t"
            "v_fma_f32 %5, %23, %25, %28\n\t"
            "v_fma_f32 %6, %23, %26, %28\n\t"
            "v_mul_f32_dpp %1, %7, %8 row_ror:1 row_mask:0xf bank_mask:0xf\n\t"
            "v_mul_f32_dpp %2, %7, %9 row_ror:2 row_mask:0xf bank_mask:0xf\n\t"
            "v_mul_f32_dpp %3, %7, %10 row_ror:3 row_mask:0xf bank_mask:0xf\n\t"
            "v_fmac_f32_dpp %0, %7, %11 row_ror:4 row_mask:0xf bank_mask:0xf\n\t"
            "v_fmac_f32_dpp %1, %7, %12 row_ror:5 row_mask:0xf bank_mask:0xf\n\t"
            "v_fmac_f32_dpp %2, %7, %13 row_ror:6 row_mask:0xf bank_mask:0xf\n\t"
            "v_fmac_f32_dpp %3, %7, %14 row_ror:7 row_mask:0xf bank_mask:0xf\n\t"
            "v_fmac_f32_dpp %0, %7, %15 row_ror:8 row_mask:0xf bank_mask:0xf\n\t"
            "v_fmac_f32_dpp %1, %7, %16 row_ror:9 row_mask:0xf bank_mask:0xf\n\t"
            "v_fmac_f32_dpp %2, %7, %17 row_ror:10 row_mask:0xf bank_mask:0xf\n\t"
            "v_fmac_f32_dpp %3, %7, %18 row_ror:11 row_mask:0xf bank_mask:0xf\n\t"
            "v_fmac_f32_dpp %0, %7, %19 row_ror:12 row_mask:0xf bank_mask:0xf\n\t"
            "v_fmac_f32_dpp %1, %7, %20 row_ror:13 row_mask:0xf bank_mask:0xf\n\t"
            "v_fmac_f32_dpp %2, %7, %21 row_ror:14 row_mask:0xf bank_mask:0xf\n\t"
            "v_fmac_f32_dpp %3, %7, %22 row_ror:15 row_mask:0xf bank_mask:0xf"
            : "+v"(acc0), "=&v"(acc1), "=&v"(acc2), "=&v"(acc3),
              "=&v"(kvx), "=&v"(kvy), "=&v"(kvc)
            : "v"(rr1),
              "v"(w16[1]),  "v"(w16[2]),  "v"(w16[3]),  "v"(w16[4]),  "v"(w16[5]),
              "v"(w16[6]),  "v"(w16[7]),  "v"(w16[8]),  "v"(w16[9]),  "v"(w16[10]),
              "v"(w16[11]), "v"(w16[12]), "v"(w16[13]), "v"(w16[14]), "v"(w16[15]),
              "v"(mF), "v"(xab.x), "v"(xab.y), "v"(xc), "v"(cvx), "v"(cB));
        float s = (acc0 + acc1) + (acc2 + acc3);

        // layer 2 tanh + layer 3 lane term, folded: p = fma(-2w2, r, w2 + b2/16)
        float e2  = __builtin_amdgcn_exp2f(s);
        float r2r = __builtin_amdgcn_rcpf(e2 + 1.0f);
        float p   = fmaf(w2m, r2r, w2p);
        // circular rotate-reduce over the 16-lane net group (ping-pong + waits)
        float q;
        asm("s_nop 1\n\t"
            "v_add_f32_dpp %1, %0, %0 row_ror:8 row_mask:0xf bank_mask:0xf\n\t"
            "s_nop 1\n\t"
            "v_add_f32_dpp %0, %1, %1 row_ror:4 row_mask:0xf bank_mask:0xf\n\t"
            "s_nop 1\n\t"
            "v_add_f32_dpp %1, %0, %0 row_ror:2 row_mask:0xf bank_mask:0xf\n\t"
            "s_nop 1\n\t"
            "v_add_f32_dpp %0, %1, %1 row_ror:1 row_mask:0xf bank_mask:0xf\n\t"
            "s_nop 1"
            : "+v"(p), "=&v"(q));
        float ov = p;
        // net exchange: r1 <-> r2 across the 16-lane row pair
#if __has_builtin(__builtin_amdgcn_permlane16_swap)
        auto pr = __builtin_amdgcn_permlane16_swap(__float_as_uint(ov), __float_as_uint(ov), false, false);
        float other = __uint_as_float(net ? pr[0] : pr[1]);
#else
        float other = SWZ(ov, 0x401F);
#endif
        float f1 = net ? other : ov;   // raw fnn1
        float f2 = net ? ov : other;   // raw fnn2

        // normalized-space physics (scalar fma chains)
        kab.x = kvx - f1;
        kab.y = fmaf(-3.0f, f2, fmaf(f1, sAB, kvy));
        kc    = kvc + f2;
    };

    // one full RK4 step (store first, then advance)
    auto step = [&](float ut) {
        float cvx = fmaf(alpha, ut, beta);
        v2f k1ab, k2ab, k3ab, k4ab;
        float k1c, k2c, k3c, k4c;
        fxu(Cab, Cc, cvx, k1ab, k1c);
        fxu(pkfma(HALF2, k1ab, Cab), fmaf(0.5f, k1c, Cc), cvx, k2ab, k2c);
        fxu(pkfma(HALF2, k2ab, Cab), fmaf(0.5f, k2c, Cc), cvx, k3ab, k3c);
        fxu(Cab + k3ab, Cc + k3c, cvx, k4ab, k4c);
        v2f   sab = pkfma(TWO2, k2ab + k3ab, k1ab) + k4ab;
        float sc  = fmaf(2.0f, k2c + k3c, k1c) + k4c;
        Cab = pkfma(SIXTH2, sab, Cab);
        Cc  = fmaf(1.0f / 6.0f, sc, Cc);
    };
    auto emit = [&]() {
        float v = selA ? Cab.x : (selB ? Cab.y : Cc);
        if (active) { *sp = v; sp += sstr; }
    };
    // load u[t4 .. t4+3] (vectorized; ubase+t4 is 16B-aligned since t4%4==0)
    float uq[4];
    auto load_u4 = [&](int t4) {
        if (vU) {
            const unsigned short* pu = (const unsigned short*)u_ + (ubase + t4);
            ushort4 raw = *reinterpret_cast<const ushort4*>(pu);
            uq[0] = bfc(raw.x); uq[1] = bfc(raw.y); uq[2] = bfc(raw.z); uq[3] = bfc(raw.w);
        } else {
            const float* pf = (const float*)u_ + (ubase + t4);
            float4 raw = *reinterpret_cast<const float4*>(pf);
            uq[0] = raw.x; uq[1] = raw.y; uq[2] = raw.z; uq[3] = raw.w;
        }
    };

    // main loop: full 4-step blocks, no per-step termination check
    for (int t4 = 0; t4 < T_STEPS - 4; t4 += 4) {
        load_u4(t4);
        #pragma unroll
        for (int tb = 0; tb < 4; ++tb) {
            emit();
            step(uq[tb]);
        }
    }
    // tail block: steps 1020..1022 advance, 1023 store-only
    load_u4(T_STEPS - 4);
    #pragma unroll
    for (int tb = 0; tb < 3; ++tb) {
        emit();
        step(uq[tb]);
    }
    emit();
}

extern "C" void kernel_launch(void* const* d_in, const int* in_sizes, int n_in,
                              void* d_out, int out_size, void* d_ws, size_t ws_size,
                              hipStream_t stream) {
    (void)in_sizes; (void)n_in; (void)out_size; (void)d_ws; (void)ws_size;
    dim3 grid(B_SEQ / 2);
    dim3 block(64);
    reac_rk4_kernel<<<grid, block, 0, stream>>>(
        d_in[0],  d_in[1],
        d_in[2],  d_in[3],  d_in[4],  d_in[5],  d_in[6],  d_in[7],
        d_in[8],  d_in[9],  d_in[10], d_in[11], d_in[12], d_in[13],
        d_in[14], d_in[15], d_in[16], d_in[17],
        (float*)d_out);
}